// Round 12
// baseline (495.703 us; speedup 1.0000x reference)
//
#include <hip/hip_runtime.h>

#define NNODE 100000
#define NEDGE 1000000
#define CAP 64

typedef __attribute__((ext_vector_type(4))) float f32x4;
typedef __attribute__((ext_vector_type(8))) short bf16x8;

__device__ __forceinline__ float lrelu(float x){ return x >= 0.f ? x : 0.2f*x; }
__device__ __forceinline__ unsigned short f2bf(float f){
    unsigned u = __float_as_uint(f);
    unsigned r = (u + 0x7FFFu + ((u >> 16) & 1u)) >> 16;
    return (unsigned short)r;
}
__device__ __forceinline__ float bf2f(unsigned short h){
    return __uint_as_float(((unsigned)h) << 16);
}

// ---- graph build ---------------------------------------------------------
__global__ void detect_kernel(const int* __restrict__ ei, int* __restrict__ flag){
    int t = threadIdx.x;                       // 64 threads
    int nz = ei[2*t + 1];                      // odd words of first 64 values
    unsigned long long b = __ballot(nz != 0);
    if (t == 0) flag[0] = (b == 0ULL) ? 1 : 0; // all-zero odd words => int64
}

__global__ __launch_bounds__(256) void scatter_kernel(const int* __restrict__ ei,
                                                      const int* __restrict__ flag,
                                                      int* __restrict__ cnt,
                                                      int* __restrict__ col){
    int e = blockIdx.x * 256 + threadIdx.x;
    if (e >= NEDGE) return;
    int s, d;
    if (flag[0]){ s = ei[2*e]; d = ei[2*(NEDGE + e)]; }
    else        { s = ei[e];   d = ei[NEDGE + e]; }
    if ((unsigned)s < NNODE && (unsigned)d < NNODE){
        int p = atomicAdd(&cnt[d], 1);
        if (p < CAP) col[d*CAP + p] = s;
    }
}

// ---- fused setup: dinv (391 blk) + foldw (72 blk) + castw2 (80 blk) ------
__global__ __launch_bounds__(256) void setup_kernel(const int* __restrict__ cnt,
                                                    float* __restrict__ dinv,
                                                    const float* __restrict__ Wssg,
                                                    const float* __restrict__ bssg,
                                                    const float* __restrict__ W1l,
                                                    const float* __restrict__ b1l,
                                                    const float* __restrict__ W1r,
                                                    const float* __restrict__ b1r,
                                                    unsigned short* __restrict__ Wct,
                                                    float* __restrict__ bc,
                                                    const float* __restrict__ W2l,
                                                    const float* __restrict__ b2l,
                                                    const float* __restrict__ W2r,
                                                    const float* __restrict__ b2r,
                                                    unsigned short* __restrict__ W2t,
                                                    float* __restrict__ b2c){
    int b = blockIdx.x;
    if (b < 391){
        int i = b * 256 + threadIdx.x;
        if (i < NNODE) dinv[i] = rsqrtf((float)(cnt[i] + 1));
    } else if (b < 463){
        int id = (b - 391) * 256 + threadIdx.x;
        if (id < 2*64*144){
            int which = id / (64*144);
            int rem = id - which*64*144;
            int k = rem / 144, j = rem - (rem/144)*144;
            const float* W1 = which ? W1r : W1l;
            float s = 0.f;
            #pragma unroll 8
            for (int c = 0; c < 64; ++c)
                s = fmaf(Wssg[k*64 + c], W1[c*144 + j], s);
            Wct[(size_t)(which*144 + j)*64 + k] = f2bf(s);
        }
        if (id < 2*144){
            int which = id / 144, j = id - which*144;
            const float* W1 = which ? W1r : W1l;
            const float* b1 = which ? b1r : b1l;
            float s = b1[j];
            #pragma unroll 8
            for (int c = 0; c < 64; ++c)
                s = fmaf(bssg[c], W1[c*144 + j], s);
            bc[which*144 + j] = s;
        }
    } else {
        int id = (b - 463) * 256 + threadIdx.x;
        if (id < 128*160){
            int j = id / 160, k = id - (id/160)*160;
            float v = 0.f;
            if (k < 144) v = (j < 64) ? W2l[k*64 + j] : W2r[k*64 + (j - 64)];
            W2t[(size_t)j*160 + k] = f2bf(v);
        }
        if (id < 128) b2c[id] = (id < 64) ? b2l[id] : b2r[id - 64];
    }
}

// ---- SSGConv gather: h = 0.5*x + 0.5*agg, bf16 out -----------------------
// 8 edge-slots x 8 lanes (8 ch each, 2x float4); end-only xor reduction.
__global__ __launch_bounds__(256) void ssg_kernel(const float* __restrict__ x,
                                                  const int* __restrict__ col,
                                                  const int* __restrict__ cnt,
                                                  const float* __restrict__ dinv,
                                                  unsigned short* __restrict__ hb){
    int wid = threadIdx.x >> 6, lane = threadIdx.x & 63;
    int d = blockIdx.x * 4 + wid;
    int cq = lane & 7, eq = lane >> 3;
    float di = dinv[d];
    int deg = min(cnt[d], CAP);
    int myc = (lane < deg) ? col[d*CAP + lane] : 0;
    float wl = (lane < deg) ? dinv[myc] : 0.f;
    float a0=0.f,a1=0.f,a2=0.f,a3=0.f,a4=0.f,a5=0.f,a6=0.f,a7=0.f;
    for (int e0 = 0; e0 < deg; e0 += 8){
        int e = e0 + eq;
        bool val = e < deg;
        int idx = val ? e : 0;
        int se = __shfl(myc, idx);
        float w = __shfl(wl, idx);
        if (!val) w = 0.f;
        float4 v0 = *(const float4*)&x[(size_t)se*64 + 8*cq];
        float4 v1 = *(const float4*)&x[(size_t)se*64 + 8*cq + 4];
        a0 = fmaf(w, v0.x, a0); a1 = fmaf(w, v0.y, a1);
        a2 = fmaf(w, v0.z, a2); a3 = fmaf(w, v0.w, a3);
        a4 = fmaf(w, v1.x, a4); a5 = fmaf(w, v1.y, a5);
        a6 = fmaf(w, v1.z, a6); a7 = fmaf(w, v1.w, a7);
    }
    #pragma unroll
    for (int m = 8; m < 64; m <<= 1){
        a0 += __shfl_xor(a0, m); a1 += __shfl_xor(a1, m);
        a2 += __shfl_xor(a2, m); a3 += __shfl_xor(a3, m);
        a4 += __shfl_xor(a4, m); a5 += __shfl_xor(a5, m);
        a6 += __shfl_xor(a6, m); a7 += __shfl_xor(a7, m);
    }
    if (eq == 0){
        float4 xd0 = *(const float4*)&x[(size_t)d*64 + 8*cq];
        float4 xd1 = *(const float4*)&x[(size_t)d*64 + 8*cq + 4];
        float dd = di*di;
        ushort4 o0, o1;
        o0.x = f2bf(0.5f*xd0.x + 0.5f*fmaf(di, a0, dd*xd0.x));
        o0.y = f2bf(0.5f*xd0.y + 0.5f*fmaf(di, a1, dd*xd0.y));
        o0.z = f2bf(0.5f*xd0.z + 0.5f*fmaf(di, a2, dd*xd0.z));
        o0.w = f2bf(0.5f*xd0.w + 0.5f*fmaf(di, a3, dd*xd0.w));
        o1.x = f2bf(0.5f*xd1.x + 0.5f*fmaf(di, a4, dd*xd1.x));
        o1.y = f2bf(0.5f*xd1.y + 0.5f*fmaf(di, a5, dd*xd1.y));
        o1.z = f2bf(0.5f*xd1.z + 0.5f*fmaf(di, a6, dd*xd1.z));
        o1.w = f2bf(0.5f*xd1.w + 0.5f*fmaf(di, a7, dd*xd1.w));
        *(ushort4*)&hb[(size_t)d*64 + 8*cq]     = o0;
        *(ushort4*)&hb[(size_t)d*64 + 8*cq + 4] = o1;
    }
}

// ---- MFMA GEMM: Y[N,OUT1+OUT2] = Xb[N,K](bf16) @ Wt^T(bf16) + Bc ---------
template<int K, int OUT1, int OUT2>
__global__ __launch_bounds__(256) void gemm_mfma_kernel(const unsigned short* __restrict__ Xb,
                                                        const unsigned short* __restrict__ Wt,
                                                        const float* __restrict__ Bc,
                                                        unsigned short* __restrict__ Y1,
                                                        unsigned short* __restrict__ Y2){
    constexpr int OUT = OUT1 + OUT2;
    constexpr int NT = OUT / 16;
    int wid = threadIdx.x >> 6, lane = threadIdx.x & 63;
    int m = lane & 15, kg = lane >> 4;
    int row0 = blockIdx.x * 64 + wid * 16;
    int rA = row0 + m; if (rA > NNODE-1) rA = NNODE-1;
    f32x4 acc[NT];
    #pragma unroll
    for (int t = 0; t < NT; ++t) acc[t] = (f32x4){0.f, 0.f, 0.f, 0.f};
    #pragma unroll
    for (int k0 = 0; k0 < K; k0 += 32){
        bf16x8 a = *(const bf16x8*)&Xb[(size_t)rA*K + k0 + 8*kg];
        #pragma unroll
        for (int t = 0; t < NT; ++t){
            bf16x8 b = *(const bf16x8*)&Wt[(size_t)(t*16 + m)*K + k0 + 8*kg];
            acc[t] = __builtin_amdgcn_mfma_f32_16x16x32_bf16(a, b, acc[t], 0, 0, 0);
        }
    }
    int rbase = row0 + 4*kg;
    #pragma unroll
    for (int t = 0; t < NT; ++t){
        int colg = t*16 + m;
        float bias = Bc[colg];
        #pragma unroll
        for (int r = 0; r < 4; ++r){
            int gr = rbase + r;
            if (gr < NNODE){
                unsigned short v = f2bf(acc[t][r] + bias);
                if (colg < OUT1) Y1[(size_t)gr*OUT1 + colg] = v;
                else             Y2[(size_t)gr*OUT2 + (colg - OUT1)] = v;
            }
        }
    }
}

// ---- GATv2 layer 1: H=12, C=12. Phase A unchanged; phase C vectorized ----
// Phase C: thread=(edge-subset eg 0..3, 4-ch group cg 0..35); ds_read_b128;
// 12=4*3 so a float4 never crosses a head. Final 4-way LDS combine.
__global__ __launch_bounds__(192) void gat1_kernel(const unsigned short* __restrict__ xl,
                                                   const unsigned short* __restrict__ xr,
                                                   const int* __restrict__ col,
                                                   const int* __restrict__ cnt,
                                                   const float* __restrict__ att,
                                                   const float* __restrict__ bias,
                                                   unsigned short* __restrict__ xg){
    __shared__ __align__(16) float V[16][148];
    __shared__ float A[16][13];
    __shared__ __align__(16) float P[4][36][4];
    __shared__ float Lp[4][12];
    __shared__ int scol[65];
    int d = blockIdx.x, t = threadIdx.x;
    int deg = min(cnt[d], CAP);
    int ne = deg + 1;
    if (t < deg) scol[t] = col[d*CAP + t];
    if (t == deg) scol[t] = d;                  // self loop
    int h = t % 12;
    int eslot = t / 12;
    float xrr[12], attr[12];
    {
        const ushort4* xrp = (const ushort4*)&xr[(size_t)d*144 + h*12];
        ushort4 q0 = xrp[0], q1 = xrp[1], q2 = xrp[2];
        xrr[0]=bf2f(q0.x); xrr[1]=bf2f(q0.y); xrr[2]=bf2f(q0.z); xrr[3]=bf2f(q0.w);
        xrr[4]=bf2f(q1.x); xrr[5]=bf2f(q1.y); xrr[6]=bf2f(q1.z); xrr[7]=bf2f(q1.w);
        xrr[8]=bf2f(q2.x); xrr[9]=bf2f(q2.y); xrr[10]=bf2f(q2.z); xrr[11]=bf2f(q2.w);
    }
    #pragma unroll
    for (int c = 0; c < 12; ++c) attr[c] = att[h*12 + c];
    int eg = t / 36, cg = t - (t/36)*36;        // phase C mapping (t<144)
    int hc = cg / 3;                            // head of channel group
    float4 acc4 = make_float4(0.f, 0.f, 0.f, 0.f);
    float l = 0.f;
    __syncthreads();
    for (int e0 = 0; e0 < ne; e0 += 16){
        int e = e0 + eslot;
        if (e < ne){
            const ushort4* row = (const ushort4*)&xl[(size_t)scol[e]*144 + h*12];
            ushort4 q0 = row[0], q1 = row[1], q2 = row[2];
            float v0=bf2f(q0.x), v1=bf2f(q0.y), v2=bf2f(q0.z), v3=bf2f(q0.w);
            float v4=bf2f(q1.x), v5=bf2f(q1.y), v6=bf2f(q1.z), v7=bf2f(q1.w);
            float v8=bf2f(q2.x), v9=bf2f(q2.y), v10=bf2f(q2.z), v11=bf2f(q2.w);
            float s = 0.f;
            s = fmaf(lrelu(v0 + xrr[0]),  attr[0],  s);
            s = fmaf(lrelu(v1 + xrr[1]),  attr[1],  s);
            s = fmaf(lrelu(v2 + xrr[2]),  attr[2],  s);
            s = fmaf(lrelu(v3 + xrr[3]),  attr[3],  s);
            s = fmaf(lrelu(v4 + xrr[4]),  attr[4],  s);
            s = fmaf(lrelu(v5 + xrr[5]),  attr[5],  s);
            s = fmaf(lrelu(v6 + xrr[6]),  attr[6],  s);
            s = fmaf(lrelu(v7 + xrr[7]),  attr[7],  s);
            s = fmaf(lrelu(v8 + xrr[8]),  attr[8],  s);
            s = fmaf(lrelu(v9 + xrr[9]),  attr[9],  s);
            s = fmaf(lrelu(v10 + xrr[10]), attr[10], s);
            s = fmaf(lrelu(v11 + xrr[11]), attr[11], s);
            A[eslot][h] = __expf(s);
            *(float4*)&V[eslot][h*12]     = make_float4(v0, v1, v2, v3);
            *(float4*)&V[eslot][h*12 + 4] = make_float4(v4, v5, v6, v7);
            *(float4*)&V[eslot][h*12 + 8] = make_float4(v8, v9, v10, v11);
        }
        __syncthreads();
        if (t < 144){
            int lim = ne - e0; if (lim > 16) lim = 16;
            for (int ee = eg; ee < lim; ee += 4){
                float a = A[ee][hc];
                float4 v = *(const float4*)&V[ee][4*cg];
                acc4.x = fmaf(a, v.x, acc4.x);
                acc4.y = fmaf(a, v.y, acc4.y);
                acc4.z = fmaf(a, v.z, acc4.z);
                acc4.w = fmaf(a, v.w, acc4.w);
                l += a;
            }
        }
        __syncthreads();
    }
    if (t < 144){
        *(float4*)&P[eg][cg][0] = acc4;
        if (cg - hc*3 == 0) Lp[eg][hc] = l;     // one writer per (eg, head)
    }
    __syncthreads();
    if (t < 144){
        int cgf = t >> 2, cif = t & 3, hh = t / 12;
        float acc = P[0][cgf][cif] + P[1][cgf][cif] + P[2][cgf][cif] + P[3][cgf][cif];
        float ll  = Lp[0][hh] + Lp[1][hh] + Lp[2][hh] + Lp[3][hh];
        xg[(size_t)d*160 + t] = f2bf(acc / (ll + 1e-16f) + bias[t]);
    } else if (t < 160){
        xg[(size_t)d*160 + t] = 0;              // zero pad for K=160 GEMM
    }
}

// ---- GATv2 layer 2: H=1, C=64, bf16 inputs, 8-edge chunks, LDS staging ---
__global__ __launch_bounds__(256) void gat2_kernel(const unsigned short* __restrict__ xl,
                                                   const unsigned short* __restrict__ xr,
                                                   const int* __restrict__ col,
                                                   const int* __restrict__ cnt,
                                                   const float* __restrict__ att,
                                                   const float* __restrict__ bias,
                                                   float* __restrict__ out){
    __shared__ float V[4][8][68];
    __shared__ float Aw[4][8];
    int wid = threadIdx.x >> 6, lane = threadIdx.x & 63;
    int d0 = blockIdx.x * 4;
    int d = d0 + wid;
    int deg = min(cnt[d], 63);
    int ne = deg + 1;
    int nemax = 1;
    #pragma unroll
    for (int j = 0; j < 4; ++j) nemax = max(nemax, min(cnt[d0+j], 63) + 1);
    int eq = lane >> 3, cq = lane & 7;         // 8 edges x 8 lanes
    float4 xra, xrb;
    {
        ushort4 u0 = *(const ushort4*)&xr[(size_t)d*64 + 8*cq];
        ushort4 u1 = *(const ushort4*)&xr[(size_t)d*64 + 8*cq + 4];
        xra = make_float4(bf2f(u0.x), bf2f(u0.y), bf2f(u0.z), bf2f(u0.w));
        xrb = make_float4(bf2f(u1.x), bf2f(u1.y), bf2f(u1.z), bf2f(u1.w));
    }
    float4 ata = *(const float4*)&att[8*cq];
    float4 atb = *(const float4*)&att[8*cq + 4];
    int myc = (lane < deg) ? col[d*CAP + lane] : d;
    float acc = 0.f, l = 0.f;
    for (int e0 = 0; e0 < nemax; e0 += 8){
        int e = e0 + eq;
        bool val = (e < ne);
        int se = __shfl(myc, val ? e : 0);
        float4 va = make_float4(0.f,0.f,0.f,0.f), vb = va;
        if (val){
            ushort4 u0 = *(const ushort4*)&xl[(size_t)se*64 + 8*cq];
            ushort4 u1 = *(const ushort4*)&xl[(size_t)se*64 + 8*cq + 4];
            va = make_float4(bf2f(u0.x), bf2f(u0.y), bf2f(u0.z), bf2f(u0.w));
            vb = make_float4(bf2f(u1.x), bf2f(u1.y), bf2f(u1.z), bf2f(u1.w));
        }
        float part = 0.f;
        part = fmaf(lrelu(va.x + xra.x), ata.x, part);
        part = fmaf(lrelu(va.y + xra.y), ata.y, part);
        part = fmaf(lrelu(va.z + xra.z), ata.z, part);
        part = fmaf(lrelu(va.w + xra.w), ata.w, part);
        part = fmaf(lrelu(vb.x + xrb.x), atb.x, part);
        part = fmaf(lrelu(vb.y + xrb.y), atb.y, part);
        part = fmaf(lrelu(vb.z + xrb.z), atb.z, part);
        part = fmaf(lrelu(vb.w + xrb.w), atb.w, part);
        part += __shfl_xor(part, 1);
        part += __shfl_xor(part, 2);
        part += __shfl_xor(part, 4);
        *(float4*)&V[wid][eq][8*cq]     = va;
        *(float4*)&V[wid][eq][8*cq + 4] = vb;
        if (cq == 0) Aw[wid][eq] = val ? __expf(part) : 0.f;
        __syncthreads();
        int lim = ne - e0; if (lim > 8) lim = 8;
        for (int j = 0; j < lim; ++j){
            float a = Aw[wid][j];
            l += a;
            acc = fmaf(a, V[wid][j][lane], acc);
        }
        __syncthreads();
    }
    out[(size_t)d*64 + lane] = acc / (l + 1e-16f) + bias[lane];
}

extern "C" void kernel_launch(void* const* d_in, const int* in_sizes, int n_in,
                              void* d_out, int out_size, void* d_ws, size_t ws_size,
                              hipStream_t stream){
    const float* feat  = (const float*)d_in[0];
    const int*   ei    = (const int*)d_in[1];
    const float* W_ssg = (const float*)d_in[2];
    const float* b_ssg = (const float*)d_in[3];
    const float* W1l   = (const float*)d_in[4];
    const float* b1l   = (const float*)d_in[5];
    const float* W1r   = (const float*)d_in[6];
    const float* b1r   = (const float*)d_in[7];
    const float* att1  = (const float*)d_in[8];
    const float* bias1 = (const float*)d_in[9];
    const float* W2l   = (const float*)d_in[10];
    const float* b2l   = (const float*)d_in[11];
    const float* W2r   = (const float*)d_in[12];
    const float* b2r   = (const float*)d_in[13];
    const float* att2  = (const float*)d_in[14];
    const float* bias2 = (const float*)d_in[15];
    float* out = (float*)d_out;

    char* ws = (char*)d_ws;
    size_t off = 0;
    auto alloc = [&](size_t bytes)->void*{
        void* p = ws + off; off = (off + bytes + 255) & ~(size_t)255; return p;
    };
    int*            flag = (int*)           alloc(4);
    int*            cnt  = (int*)           alloc((size_t)NNODE*4);
    int*            col  = (int*)           alloc((size_t)NNODE*CAP*4);
    float*          dinv = (float*)         alloc((size_t)NNODE*4);
    unsigned short* hb   = (unsigned short*)alloc((size_t)NNODE*64*2);
    unsigned short* xl1b = (unsigned short*)alloc((size_t)NNODE*144*2);
    unsigned short* xr1b = (unsigned short*)alloc((size_t)NNODE*144*2);
    unsigned short* xg   = (unsigned short*)alloc((size_t)NNODE*160*2);
    unsigned short* xl2b = (unsigned short*)alloc((size_t)NNODE*64*2);
    unsigned short* xr2b = (unsigned short*)alloc((size_t)NNODE*64*2);
    unsigned short* Wct  = (unsigned short*)alloc((size_t)288*64*2);
    float*          bc   = (float*)         alloc((size_t)288*4);
    unsigned short* W2t  = (unsigned short*)alloc((size_t)128*160*2);
    float*          b2c  = (float*)         alloc((size_t)128*4);

    hipMemsetAsync(cnt, 0, (size_t)NNODE*4, stream);
    detect_kernel<<<1, 64, 0, stream>>>(ei, flag);
    scatter_kernel<<<(NEDGE + 255)/256, 256, 0, stream>>>(ei, flag, cnt, col);
    setup_kernel<<<543, 256, 0, stream>>>(cnt, dinv,
                                          W_ssg, b_ssg, W1l, b1l, W1r, b1r, Wct, bc,
                                          W2l, b2l, W2r, b2r, W2t, b2c);

    ssg_kernel<<<NNODE/4, 256, 0, stream>>>(feat, col, cnt, dinv, hb);

    gemm_mfma_kernel<64,144,144><<<1563, 256, 0, stream>>>(hb, Wct, bc, xl1b, xr1b);

    gat1_kernel<<<NNODE, 192, 0, stream>>>(xl1b, xr1b, col, cnt, att1, bias1, xg);

    gemm_mfma_kernel<160,64,64><<<1563, 256, 0, stream>>>(xg, W2t, b2c, xl2b, xr2b);

    gat2_kernel<<<NNODE/4, 256, 0, stream>>>(xl2b, xr2b, col, cnt, att2, bias2, out);
}